// Round 2
// baseline (362.370 us; speedup 1.0000x reference)
//
#include <hip/hip_runtime.h>
#include <cstdint>
#include <cstddef>

#define NB 16
#define SIDE 160
#define MM (SIDE*SIDE)      // 25600 anchors
#define NC 80
#define NG 32
#define TOPK 10
#define REGW 3.0f
#define INVC 1e9f

using ull = unsigned long long;

__device__ __forceinline__ unsigned f2sort(float f) {
    unsigned b = __float_as_uint(f);
    return b ^ ((unsigned)((int)b >> 31) | 0x80000000u);
}
__device__ __forceinline__ float sort2f(unsigned s) {
    unsigned b = s ^ ((s & 0x80000000u) ? 0x80000000u : 0xFFFFFFFFu);
    return __uint_as_float(b);
}
__device__ __forceinline__ ull shflx64(ull v, int m) {
    int lo = __shfl_xor((int)(unsigned)v, m);
    int hi = __shfl_xor((int)(unsigned)(v >> 32), m);
    return ((ull)(unsigned)hi << 32) | (unsigned)lo;
}
__device__ __forceinline__ float f_bg(float x) {
    float e  = expf(-fabsf(x));
    float rc = 1.f/(1.f+e);
    float p  = (x >= 0.f) ? rc : e*rc;        // sigmoid(x)
    float sp = fmaxf(x, 0.f) + log1pf(e);     // softplus(x)
    return sp*p*p*0.75f;
}
__device__ __forceinline__ float f_fg(float x) {
    float e  = expf(-fabsf(x));
    float rc = 1.f/(1.f+e);
    float p  = (x >= 0.f) ? rc : e*rc;
    float sp = fmaxf(x, 0.f) + log1pf(e);
    float om = 1.f - p;
    return (sp - x)*om*om*0.25f;              // softplus(-x)*(1-p)^2*alpha
}

// ============ fused: valid + cost/iou top-10 partials + bg focal sum ========
__global__ __launch_bounds__(256, 3) void k_cost(
    const float* __restrict__ pred_cls, const float* __restrict__ pred_box,
    const float* __restrict__ gt_boxes, const int* __restrict__ gt_labels,
    const unsigned char* __restrict__ mask,
    ull* __restrict__ cost_part, ull* __restrict__ iou_part,
    float* __restrict__ accum, int nchunk)
{
    __shared__ float s_cls[128*82];     // 41,984 B (stride 82 -> bounded conflicts)
    __shared__ float4 s_box[128];
    __shared__ unsigned s_vm[256];
    __shared__ unsigned s_orm[8];
    __shared__ float s_gtb[128];
    __shared__ int s_lab[32];
    __shared__ unsigned char s_msk[128];
    __shared__ float s_red[4];

    int blk = blockIdx.x;
    int b = blk / nchunk, chunk = blk - b*nchunk;
    int A = MM / nchunk;                // 512 (nchunk=50) or 1024 (25)
    int nsub = A >> 7;
    int tid = threadIdx.x;
    int g = tid >> 3, j = tid & 7;

    if (tid < 128) s_gtb[tid] = gt_boxes[b*NG*4 + tid];
    if (tid < 32)  s_lab[tid] = gt_labels[b*NG + tid];
    __syncthreads();
    float gx1 = s_gtb[g*4+0], gy1 = s_gtb[g*4+1];
    float gx2 = s_gtb[g*4+2], gy2 = s_gtb[g*4+3];
    int   lab = s_lab[g];
    float garea = (gx2-gx1)*(gy2-gy1);

    ull lc[TOPK], li[TOPK];
    #pragma unroll
    for (int t = 0; t < TOPK; ++t) { lc[t] = ~0ull; li[t] = ~0ull; }
    float bgsum = 0.f;

    int m0 = chunk * A;
    for (int s = 0; s < nsub; ++s) {
        int mbase = m0 + s*128;
        const float4* gcls = (const float4*)(pred_cls + ((size_t)b*MM + mbase)*NC);
        __syncthreads();                 // LDS free from previous subtile
        #pragma unroll
        for (int q = 0; q < 10; ++q) {   // 2560 float4s, fully coalesced
            int idx = tid + 256*q;
            float4 v = gcls[idx];
            int a = idx / 20, c4 = (idx - a*20)*4;
            float* d = &s_cls[a*82 + c4];
            d[0]=v.x; d[1]=v.y; d[2]=v.z; d[3]=v.w;
        }
        if (tid < 128) {
            s_box[tid] = ((const float4*)pred_box)[(size_t)b*MM + mbase + tid];
            s_msk[tid] = mask[(size_t)b*MM + mbase + tid];
        }
        __syncthreads();
        // ---- anchor-inside-gt bits for my g (anchor coords analytic) ----
        unsigned vm = 0;
        #pragma unroll
        for (int k = 0; k < 16; ++k) {
            int a = j + 8*k;
            int m = mbase + a;
            int row = m / SIDE;
            int col = m - row*SIDE;
            float ax = (col + 0.5f) * 8.0f;
            float ay = (row + 0.5f) * 8.0f;
            float d0 = fminf(fminf(ax-gx1, ay-gy1), fminf(gx2-ax, gy2-ay));
            vm |= (d0 > 0.f) ? (1u<<k) : 0u;
        }
        s_vm[tid] = vm;
        __syncthreads();
        if (tid < 8) {
            unsigned o = 0;
            for (int gg = 0; gg < 32; ++gg) o |= s_vm[gg*8 + tid];
            s_orm[tid] = o;
        }
        __syncthreads();
        unsigned orm = s_orm[j];
        // ---- cost + iou, per-thread register top-10 ----
        #pragma unroll
        for (int k = 0; k < 16; ++k) {
            int a = j + 8*k;
            unsigned m = (unsigned)(mbase + a);
            float4 pb = s_box[a];
            float iw = fmaxf(fminf(gx2, pb.z) - fmaxf(gx1, pb.x), 0.f);
            float ih = fmaxf(fminf(gy2, pb.w) - fmaxf(gy1, pb.y), 0.f);
            float inter = iw*ih;
            float pa = (pb.z-pb.x)*(pb.w-pb.y);
            float uni = garea + pa - inter;
            float iou = inter / fmaxf(uni, 1e-8f);
            float l = s_cls[a*82 + lab];
            float e  = expf(-fabsf(l));
            float rc = 1.f/(1.f+e);
            float sg = (l >= 0.f) ? rc : e*rc;
            float sp_pos = fmaxf(l, 0.f) + log1pf(e);
            float sp_neg = sp_pos - l;
            float bce = iou*sp_neg + (1.f-iou)*sp_pos;
            float dd = iou - sg;
            float cost = bce*dd*dd + REGW*(-logf(iou + 1e-8f));
            if (!((orm >> k) & 1u)) cost = INVC;
            ull ck = ((ull)f2sort(cost) << 32) | m;
            if (ck < lc[TOPK-1]) {
                ull cur = ck;
                #pragma unroll
                for (int t = 0; t < TOPK; ++t) {
                    ull mn = lc[t] < cur ? lc[t] : cur;
                    ull mx = lc[t] < cur ? cur : lc[t];
                    lc[t] = mn; cur = mx;
                }
            }
            ull ik = ((ull)(~f2sort(iou)) << 32) | m;
            if (ik < li[TOPK-1]) {
                ull cur = ik;
                #pragma unroll
                for (int t = 0; t < TOPK; ++t) {
                    ull mn = li[t] < cur ? li[t] : cur;
                    ull mx = li[t] < cur ? cur : li[t];
                    li[t] = mn; cur = mx;
                }
            }
        }
        // ---- background focal sum over all 80 classes ----
        {
            int a = tid & 127, h = tid >> 7;
            if (!s_msk[a]) {
                float acc = 0.f;
                int c0 = h*40;
                for (int c = c0; c < c0+40; ++c) acc += f_bg(s_cls[a*82 + c]);
                bgsum += acc;
            }
        }
    }
    // ---- merge per-thread lists within the 8-lane group; j==0 writes ----
    size_t pbase = ((size_t)(b*NG + g)*nchunk + chunk)*TOPK;
    #pragma unroll
    for (int r = 0; r < TOPK; ++r) {
        ull h = lc[0];
        { ull o=shflx64(h,1); h=o<h?o:h; o=shflx64(h,2); h=o<h?o:h; o=shflx64(h,4); h=o<h?o:h; }
        if (lc[0] == h) {
            #pragma unroll
            for (int t = 0; t < TOPK-1; ++t) lc[t] = lc[t+1];
            lc[TOPK-1] = ~0ull;
        }
        if (j == 0) cost_part[pbase + r] = h;
    }
    #pragma unroll
    for (int r = 0; r < TOPK; ++r) {
        ull h = li[0];
        { ull o=shflx64(h,1); h=o<h?o:h; o=shflx64(h,2); h=o<h?o:h; o=shflx64(h,4); h=o<h?o:h; }
        if (li[0] == h) {
            #pragma unroll
            for (int t = 0; t < TOPK-1; ++t) li[t] = li[t+1];
            li[TOPK-1] = ~0ull;
        }
        if (j == 0) iou_part[pbase + r] = h;
    }
    // ---- block reduce bg focal sum ----
    for (int o = 32; o; o >>= 1) bgsum += __shfl_down(bgsum, o);
    int ln = tid & 63, wv = tid >> 6;
    if (ln == 0) s_red[wv] = bgsum;
    __syncthreads();
    if (tid == 0) atomicAdd(&accum[0], s_red[0]+s_red[1]+s_red[2]+s_red[3]);
}

// ============ per-(b,g) wave: dyn_k + global top-10 + scatter ===============
__global__ __launch_bounds__(256) void k_merge(
    const ull* __restrict__ cost_part, const ull* __restrict__ iou_part,
    ull* __restrict__ best, int nchunk)
{
    int lane = threadIdx.x & 63, wv = threadIdx.x >> 6;
    int bg = blockIdx.x*4 + wv;
    int b = bg >> 5, g = bg & (NG-1);
    int nent = nchunk * TOPK;           // <= 500
    size_t base = (size_t)bg * nent;

    ull l8[8];
    // ---- iou partials -> dyn_k ----
    #pragma unroll
    for (int t = 0; t < 8; ++t) l8[t] = ~0ull;
    #pragma unroll
    for (int q = 0; q < 8; ++q) {
        int e = lane + 64*q;
        ull v = (e < nent) ? iou_part[base + e] : ~0ull;
        if (v < l8[7]) {
            ull cur = v;
            #pragma unroll
            for (int t = 0; t < 8; ++t) { ull mn=l8[t]<cur?l8[t]:cur; ull mx=l8[t]<cur?cur:l8[t]; l8[t]=mn; cur=mx; }
        }
    }
    float isum = 0.f;
    #pragma unroll
    for (int r = 0; r < TOPK; ++r) {
        ull h = l8[0];
        #pragma unroll
        for (int mlt = 1; mlt < 64; mlt <<= 1) { ull o = shflx64(h, mlt); h = o<h?o:h; }
        if (l8[0] == h) {
            #pragma unroll
            for (int t = 0; t < 7; ++t) l8[t] = l8[t+1];
            l8[7] = ~0ull;
        }
        isum += sort2f(~(unsigned)(h >> 32));
    }
    int dynk = (int)isum; if (dynk < 1) dynk = 1;   // <=10 since iou<=1

    // ---- cost partials -> top-10, scatter rank<dynk ----
    #pragma unroll
    for (int t = 0; t < 8; ++t) l8[t] = ~0ull;
    #pragma unroll
    for (int q = 0; q < 8; ++q) {
        int e = lane + 64*q;
        ull v = (e < nent) ? cost_part[base + e] : ~0ull;
        if (v < l8[7]) {
            ull cur = v;
            #pragma unroll
            for (int t = 0; t < 8; ++t) { ull mn=l8[t]<cur?l8[t]:cur; ull mx=l8[t]<cur?cur:l8[t]; l8[t]=mn; cur=mx; }
        }
    }
    ull mykey = ~0ull;
    #pragma unroll
    for (int r = 0; r < TOPK; ++r) {
        ull h = l8[0];
        #pragma unroll
        for (int mlt = 1; mlt < 64; mlt <<= 1) { ull o = shflx64(h, mlt); h = o<h?o:h; }
        if (l8[0] == h) {
            #pragma unroll
            for (int t = 0; t < 7; ++t) l8[t] = l8[t+1];
            l8[7] = ~0ull;
        }
        if (lane == r) mykey = h;
    }
    if (lane < dynk) {
        unsigned m  = (unsigned)mykey;
        unsigned cb = (unsigned)(mykey >> 32);
        atomicMin(&best[(size_t)b*MM + m], ((ull)cb << 32) | (unsigned)g);
    }
}

// ============ per-anchor: giou + fg count + focal fg correction =============
__global__ __launch_bounds__(256) void k_post(
    const float* __restrict__ pred_cls, const float* __restrict__ pred_box,
    const float* __restrict__ gt_boxes, const int* __restrict__ gt_labels,
    const unsigned char* __restrict__ mask, const ull* __restrict__ best,
    float* __restrict__ accum)
{
    int i = blockIdx.x*256 + threadIdx.x;   // exact grid
    int b = i / MM;
    ull key = best[i];
    float cls_c = 0.f, giou_c = 0.f, cnt = 0.f;
    if (key != ~0ull) {
        int g = (int)(key & 0xFFFFFFFFull);
        int bgi = b*NG + g;
        float4 pb = *(const float4*)(pred_box + (size_t)i*4);
        float gx1 = gt_boxes[bgi*4],   gy1 = gt_boxes[bgi*4+1];
        float gx2 = gt_boxes[bgi*4+2], gy2 = gt_boxes[bgi*4+3];
        float iw = fmaxf(fminf(pb.z,gx2) - fmaxf(pb.x,gx1), 0.f);
        float ih = fmaxf(fminf(pb.w,gy2) - fmaxf(pb.y,gy1), 0.f);
        float inter = iw*ih;
        float a1 = fmaxf(pb.z-pb.x,0.f)*fmaxf(pb.w-pb.y,0.f);
        float a2 = fmaxf(gx2-gx1,0.f)*fmaxf(gy2-gy1,0.f);
        float uni = a1 + a2 - inter;
        float iou = inter / fmaxf(uni, 1e-7f);
        float cw = fmaxf(fmaxf(pb.z,gx2) - fminf(pb.x,gx1), 0.f);
        float ch = fmaxf(fmaxf(pb.w,gy2) - fminf(pb.y,gy1), 0.f);
        float ca = fmaxf(cw*ch, 1e-7f);
        float giou = iou - (ca - uni)/ca;
        giou_c = 1.f - giou;
        cnt = 1.f;
        if (!mask[i]) {
            int lab = gt_labels[bgi];
            float x = pred_cls[(size_t)i*NC + lab];
            cls_c = f_fg(x) - f_bg(x);      // replace bg term with fg term
        }
    }
    for (int o = 32; o; o >>= 1) {
        cls_c  += __shfl_down(cls_c, o);
        giou_c += __shfl_down(giou_c, o);
        cnt    += __shfl_down(cnt, o);
    }
    __shared__ float sc[4], sg_[4], sn[4];
    int ln = threadIdx.x & 63, wv = threadIdx.x >> 6;
    if (ln == 0) { sc[wv] = cls_c; sg_[wv] = giou_c; sn[wv] = cnt; }
    __syncthreads();
    if (threadIdx.x == 0) {
        atomicAdd(&accum[0], sc[0]+sc[1]+sc[2]+sc[3]);
        float gtot = sg_[0]+sg_[1]+sg_[2]+sg_[3];
        float ntot = sn[0]+sn[1]+sn[2]+sn[3];
        if (gtot != 0.f || ntot != 0.f) {
            atomicAdd(&accum[1], gtot);
            atomicAdd(&accum[2], ntot);
        }
    }
}

__global__ void k_final(const float* __restrict__ accum, float* __restrict__ out) {
    if (threadIdx.x == 0) {
        float nf = fmaxf(accum[2], 1.f);
        out[0] = accum[0]/nf;
        out[1] = accum[1]/nf;
    }
}

extern "C" void kernel_launch(void* const* d_in, const int* in_sizes, int n_in,
                              void* d_out, int out_size, void* d_ws, size_t ws_size,
                              hipStream_t stream) {
    const float* pred_cls  = (const float*)d_in[0];
    const float* pred_box  = (const float*)d_in[1];
    const float* gt_boxes  = (const float*)d_in[3];
    const int*   gt_labels = (const int*)d_in[4];
    const unsigned char* mask = (const unsigned char*)d_in[5];
    float* out = (float*)d_out;

    auto need = [](int nc) -> size_t {
        return 256 + (size_t)NB*MM*8 + 2*(size_t)NB*NG*nc*TOPK*8;
    };
    int nchunk = 50;
    if (ws_size < need(50)) nchunk = 25;
    if (ws_size < need(25)) return;     // visible failure rather than corruption

    char* ws = (char*)d_ws;
    float* accum = (float*)ws;                                   // 256 B reserved
    ull* best      = (ull*)(ws + 256);                           // NB*MM ulls
    ull* cost_part = (ull*)(ws + 256 + (size_t)NB*MM*8);
    ull* iou_part  = cost_part + (size_t)NB*NG*nchunk*TOPK;

    hipMemsetAsync(accum, 0, 16, stream);
    hipMemsetAsync(best, 0xFF, (size_t)NB*MM*8, stream);

    k_cost <<<NB*nchunk, 256, 0, stream>>>(pred_cls, pred_box, gt_boxes, gt_labels,
                                           mask, cost_part, iou_part, accum, nchunk);
    k_merge<<<NB*NG/4,   256, 0, stream>>>(cost_part, iou_part, best, nchunk);
    k_post <<<NB*MM/256, 256, 0, stream>>>(pred_cls, pred_box, gt_boxes, gt_labels,
                                           mask, best, accum);
    k_final<<<1, 64, 0, stream>>>(accum, out);
}

// Round 3
// 244.317 us; speedup vs baseline: 1.4832x; 1.4832x over previous
//
#include <hip/hip_runtime.h>
#include <cstdint>
#include <cstddef>

#define NB 16
#define SIDE 160
#define MM (SIDE*SIDE)      // 25600 anchors
#define NC 80
#define NG 32
#define TOPK 10
#define REGW 3.0f
#define INVC 1e9f

using ull = unsigned long long;

__device__ __forceinline__ unsigned f2sort(float f) {
    unsigned b = __float_as_uint(f);
    return b ^ ((unsigned)((int)b >> 31) | 0x80000000u);
}
__device__ __forceinline__ float sort2f(unsigned s) {
    unsigned b = s ^ ((s & 0x80000000u) ? 0x80000000u : 0xFFFFFFFFu);
    return __uint_as_float(b);
}
__device__ __forceinline__ ull shflx64(ull v, int m) {
    int lo = __shfl_xor((int)(unsigned)v, m);
    int hi = __shfl_xor((int)(unsigned)(v >> 32), m);
    return ((ull)(unsigned)hi << 32) | (unsigned)lo;
}
__device__ __forceinline__ float rcpf(float x) { return __builtin_amdgcn_rcpf(x); }

__device__ __forceinline__ float f_bg(float x) {
    float e  = __expf(-fabsf(x));
    float rc = rcpf(1.f + e);
    float p  = (x >= 0.f) ? rc : e*rc;        // sigmoid(x)
    float sp = fmaxf(x, 0.f) + __logf(1.f + e);  // softplus(x)
    return sp*p*p*0.75f;
}
__device__ __forceinline__ float f_fg(float x) {
    float e  = __expf(-fabsf(x));
    float rc = rcpf(1.f + e);
    float p  = (x >= 0.f) ? rc : e*rc;
    float sp = fmaxf(x, 0.f) + __logf(1.f + e);
    float om = 1.f - p;
    return (sp - x)*om*om*0.25f;              // softplus(-x)*(1-p)^2*alpha
}

// ============ fused: valid + cost/iou top-10 partials + bg focal sum ========
__global__ __launch_bounds__(256, 5) void k_cost(
    const float* __restrict__ pred_cls, const float* __restrict__ pred_box,
    const float* __restrict__ gt_boxes, const int* __restrict__ gt_labels,
    const unsigned char* __restrict__ mask,
    ull* __restrict__ cost_part, ull* __restrict__ iou_part,
    float* __restrict__ accum, int nchunk)
{
    __shared__ float s_cls[64*33];      // label columns only: 8448 B
    __shared__ float4 s_box[64];
    __shared__ unsigned s_vm[256];
    __shared__ unsigned s_orm[8];
    __shared__ float s_gtb[128];
    __shared__ int s_lab[32];
    __shared__ int s_slot[80];
    __shared__ float s_red[4];

    int blk = blockIdx.x;
    int b = blk / nchunk, chunk = blk - b*nchunk;
    int A = MM / nchunk;                // 512 (nchunk=50)
    int nsub = A >> 6;
    int tid = threadIdx.x;
    int g = tid >> 3, j = tid & 7;

    if (tid < 128) s_gtb[tid] = gt_boxes[b*NG*4 + tid];
    if (tid < 32)  s_lab[tid] = gt_labels[b*NG + tid];
    if (tid < 80)  s_slot[tid] = 9999;
    __syncthreads();
    if (tid < 32) atomicMin(&s_slot[s_lab[tid]], tid);   // lowest-g slot per class
    __syncthreads();

    float gx1 = s_gtb[g*4+0], gy1 = s_gtb[g*4+1];
    float gx2 = s_gtb[g*4+2], gy2 = s_gtb[g*4+3];
    int slot = s_slot[s_lab[g]];        // < 32 always (own g qualifies)
    float garea = (gx2-gx1)*(gy2-gy1);

    ull lc[TOPK], li[TOPK];
    #pragma unroll
    for (int t = 0; t < TOPK; ++t) { lc[t] = ~0ull; li[t] = ~0ull; }
    float bgsum = 0.f;

    int m0 = chunk * A;
    for (int s = 0; s < nsub; ++s) {
        int mbase = m0 + s*64;
        size_t gbase = (size_t)b*MM + mbase;
        __syncthreads();                 // prior subtile's LDS reads done
        if (tid < 64) s_box[tid] = ((const float4*)pred_box)[gbase + tid];
        const float4* gcls = (const float4*)(pred_cls + gbase*NC);
        #pragma unroll
        for (int q = 0; q < 5; ++q) {    // 1280 float4s, coalesced
            int idx = tid + 256*q;
            float4 v = gcls[idx];
            int a = idx / 20, c0 = (idx - a*20)*4;
            int t0 = s_slot[c0], t1 = s_slot[c0+1], t2 = s_slot[c0+2], t3 = s_slot[c0+3];
            if (t0 < 64) s_cls[a*33 + t0] = v.x;
            if (t1 < 64) s_cls[a*33 + t1] = v.y;
            if (t2 < 64) s_cls[a*33 + t2] = v.z;
            if (t3 < 64) s_cls[a*33 + t3] = v.w;
            if (!mask[gbase + a])        // focal directly from staging registers
                bgsum += f_bg(v.x) + f_bg(v.y) + f_bg(v.z) + f_bg(v.w);
        }
        // anchor-inside-gt bits for my g (analytic anchor coords)
        unsigned vm = 0;
        #pragma unroll
        for (int k = 0; k < 8; ++k) {
            int m = mbase + j + 8*k;
            int row = m / SIDE, col = m - row*SIDE;
            float ax = (col + 0.5f)*8.0f, ay = (row + 0.5f)*8.0f;
            float d0 = fminf(fminf(ax-gx1, ay-gy1), fminf(gx2-ax, gy2-ay));
            vm |= (d0 > 0.f) ? (1u<<k) : 0u;
        }
        s_vm[tid] = vm;
        __syncthreads();                 // s_vm, s_cls, s_box ready
        if (tid < 8) {
            unsigned o = 0;
            #pragma unroll
            for (int gg = 0; gg < 32; ++gg) o |= s_vm[gg*8 + tid];
            s_orm[tid] = o;
        }
        __syncthreads();                 // s_orm ready
        unsigned orm = s_orm[j];
        #pragma unroll
        for (int k = 0; k < 8; ++k) {
            int a = j + 8*k;
            unsigned m = (unsigned)(mbase + a);
            float4 pb = s_box[a];
            float iw = fmaxf(fminf(gx2, pb.z) - fmaxf(gx1, pb.x), 0.f);
            float ih = fmaxf(fminf(gy2, pb.w) - fmaxf(gy1, pb.y), 0.f);
            float inter = iw*ih;
            float pa = (pb.z-pb.x)*(pb.w-pb.y);
            float uni = garea + pa - inter;
            float iou = inter * rcpf(fmaxf(uni, 1e-8f));
            float l = s_cls[a*33 + slot];
            float e  = __expf(-fabsf(l));
            float rc = rcpf(1.f + e);
            float sg = (l >= 0.f) ? rc : e*rc;
            float sp_pos = fmaxf(l, 0.f) + __logf(1.f + e);
            float sp_neg = sp_pos - l;
            float bce = iou*sp_neg + (1.f-iou)*sp_pos;
            float dd = iou - sg;
            float cost = bce*dd*dd - REGW*__logf(iou + 1e-8f);
            if (!((orm >> k) & 1u)) cost = INVC;
            ull ck = ((ull)f2sort(cost) << 32) | m;
            if (ck < lc[TOPK-1]) {
                ull cur = ck;
                #pragma unroll
                for (int t = 0; t < TOPK; ++t) {
                    ull mn = lc[t] < cur ? lc[t] : cur;
                    ull mx = lc[t] < cur ? cur : lc[t];
                    lc[t] = mn; cur = mx;
                }
            }
            ull ik = ((ull)(~f2sort(iou)) << 32) | m;
            if (ik < li[TOPK-1]) {
                ull cur = ik;
                #pragma unroll
                for (int t = 0; t < TOPK; ++t) {
                    ull mn = li[t] < cur ? li[t] : cur;
                    ull mx = li[t] < cur ? cur : li[t];
                    li[t] = mn; cur = mx;
                }
            }
        }
    }
    // ---- merge per-thread lists within the 8-lane group; j==0 writes ----
    size_t pbase = ((size_t)(b*NG + g)*nchunk + chunk)*TOPK;
    #pragma unroll
    for (int r = 0; r < TOPK; ++r) {
        ull h = lc[0];
        { ull o=shflx64(h,1); h=o<h?o:h; o=shflx64(h,2); h=o<h?o:h; o=shflx64(h,4); h=o<h?o:h; }
        if (lc[0] == h) {
            #pragma unroll
            for (int t = 0; t < TOPK-1; ++t) lc[t] = lc[t+1];
            lc[TOPK-1] = ~0ull;
        }
        if (j == 0) cost_part[pbase + r] = h;
    }
    #pragma unroll
    for (int r = 0; r < TOPK; ++r) {
        ull h = li[0];
        { ull o=shflx64(h,1); h=o<h?o:h; o=shflx64(h,2); h=o<h?o:h; o=shflx64(h,4); h=o<h?o:h; }
        if (li[0] == h) {
            #pragma unroll
            for (int t = 0; t < TOPK-1; ++t) li[t] = li[t+1];
            li[TOPK-1] = ~0ull;
        }
        if (j == 0) iou_part[pbase + r] = h;
    }
    // ---- block reduce bg focal sum ----
    for (int o = 32; o; o >>= 1) bgsum += __shfl_down(bgsum, o);
    int ln = tid & 63, wv = tid >> 6;
    if (ln == 0) s_red[wv] = bgsum;
    __syncthreads();
    if (tid == 0) atomicAdd(&accum[0], s_red[0]+s_red[1]+s_red[2]+s_red[3]);
}

// ============ per-(b,g) wave: dyn_k + global top-10 + scatter ===============
__global__ __launch_bounds__(256) void k_merge(
    const ull* __restrict__ cost_part, const ull* __restrict__ iou_part,
    ull* __restrict__ best, int nchunk)
{
    int lane = threadIdx.x & 63, wv = threadIdx.x >> 6;
    int bg = blockIdx.x*4 + wv;
    int b = bg >> 5, g = bg & (NG-1);
    int nent = nchunk * TOPK;           // <= 500
    size_t base = (size_t)bg * nent;

    ull l8[8];
    // ---- iou partials -> dyn_k ----
    #pragma unroll
    for (int t = 0; t < 8; ++t) l8[t] = ~0ull;
    #pragma unroll
    for (int q = 0; q < 8; ++q) {
        int e = lane + 64*q;
        ull v = (e < nent) ? iou_part[base + e] : ~0ull;
        if (v < l8[7]) {
            ull cur = v;
            #pragma unroll
            for (int t = 0; t < 8; ++t) { ull mn=l8[t]<cur?l8[t]:cur; ull mx=l8[t]<cur?cur:l8[t]; l8[t]=mn; cur=mx; }
        }
    }
    float isum = 0.f;
    #pragma unroll
    for (int r = 0; r < TOPK; ++r) {
        ull h = l8[0];
        #pragma unroll
        for (int mlt = 1; mlt < 64; mlt <<= 1) { ull o = shflx64(h, mlt); h = o<h?o:h; }
        if (l8[0] == h) {
            #pragma unroll
            for (int t = 0; t < 7; ++t) l8[t] = l8[t+1];
            l8[7] = ~0ull;
        }
        isum += sort2f(~(unsigned)(h >> 32));
    }
    int dynk = (int)isum; if (dynk < 1) dynk = 1;

    // ---- cost partials -> top-10, scatter rank<dynk ----
    #pragma unroll
    for (int t = 0; t < 8; ++t) l8[t] = ~0ull;
    #pragma unroll
    for (int q = 0; q < 8; ++q) {
        int e = lane + 64*q;
        ull v = (e < nent) ? cost_part[base + e] : ~0ull;
        if (v < l8[7]) {
            ull cur = v;
            #pragma unroll
            for (int t = 0; t < 8; ++t) { ull mn=l8[t]<cur?l8[t]:cur; ull mx=l8[t]<cur?cur:l8[t]; l8[t]=mn; cur=mx; }
        }
    }
    ull mykey = ~0ull;
    #pragma unroll
    for (int r = 0; r < TOPK; ++r) {
        ull h = l8[0];
        #pragma unroll
        for (int mlt = 1; mlt < 64; mlt <<= 1) { ull o = shflx64(h, mlt); h = o<h?o:h; }
        if (l8[0] == h) {
            #pragma unroll
            for (int t = 0; t < 7; ++t) l8[t] = l8[t+1];
            l8[7] = ~0ull;
        }
        if (lane == r) mykey = h;
    }
    if (lane < dynk) {
        unsigned m  = (unsigned)mykey;
        unsigned cb = (unsigned)(mykey >> 32);
        atomicMin(&best[(size_t)b*MM + m], ((ull)cb << 32) | (unsigned)g);
    }
}

// ============ per-anchor: giou + fg count + focal fg correction =============
__global__ __launch_bounds__(256) void k_post(
    const float* __restrict__ pred_cls, const float* __restrict__ pred_box,
    const float* __restrict__ gt_boxes, const int* __restrict__ gt_labels,
    const unsigned char* __restrict__ mask, const ull* __restrict__ best,
    float* __restrict__ accum)
{
    int i = blockIdx.x*256 + threadIdx.x;   // exact grid
    int b = i / MM;
    ull key = best[i];
    float cls_c = 0.f, giou_c = 0.f, cnt = 0.f;
    if (key != ~0ull) {
        int g = (int)(key & 0xFFFFFFFFull);
        int bgi = b*NG + g;
        float4 pb = *(const float4*)(pred_box + (size_t)i*4);
        float gx1 = gt_boxes[bgi*4],   gy1 = gt_boxes[bgi*4+1];
        float gx2 = gt_boxes[bgi*4+2], gy2 = gt_boxes[bgi*4+3];
        float iw = fmaxf(fminf(pb.z,gx2) - fmaxf(pb.x,gx1), 0.f);
        float ih = fmaxf(fminf(pb.w,gy2) - fmaxf(pb.y,gy1), 0.f);
        float inter = iw*ih;
        float a1 = fmaxf(pb.z-pb.x,0.f)*fmaxf(pb.w-pb.y,0.f);
        float a2 = fmaxf(gx2-gx1,0.f)*fmaxf(gy2-gy1,0.f);
        float uni = a1 + a2 - inter;
        float iou = inter / fmaxf(uni, 1e-7f);
        float cw = fmaxf(fmaxf(pb.z,gx2) - fminf(pb.x,gx1), 0.f);
        float ch = fmaxf(fmaxf(pb.w,gy2) - fminf(pb.y,gy1), 0.f);
        float ca = fmaxf(cw*ch, 1e-7f);
        float giou = iou - (ca - uni)/ca;
        giou_c = 1.f - giou;
        cnt = 1.f;
        if (!mask[i]) {
            int lab = gt_labels[bgi];
            float x = pred_cls[(size_t)i*NC + lab];
            cls_c = f_fg(x) - f_bg(x);      // replace bg term with fg term
        }
    }
    for (int o = 32; o; o >>= 1) {
        cls_c  += __shfl_down(cls_c, o);
        giou_c += __shfl_down(giou_c, o);
        cnt    += __shfl_down(cnt, o);
    }
    __shared__ float sc[4], sg_[4], sn[4];
    int ln = threadIdx.x & 63, wv = threadIdx.x >> 6;
    if (ln == 0) { sc[wv] = cls_c; sg_[wv] = giou_c; sn[wv] = cnt; }
    __syncthreads();
    if (threadIdx.x == 0) {
        atomicAdd(&accum[0], sc[0]+sc[1]+sc[2]+sc[3]);
        float gtot = sg_[0]+sg_[1]+sg_[2]+sg_[3];
        float ntot = sn[0]+sn[1]+sn[2]+sn[3];
        if (gtot != 0.f || ntot != 0.f) {
            atomicAdd(&accum[1], gtot);
            atomicAdd(&accum[2], ntot);
        }
    }
}

__global__ void k_final(const float* __restrict__ accum, float* __restrict__ out) {
    if (threadIdx.x == 0) {
        float nf = fmaxf(accum[2], 1.f);
        out[0] = accum[0]/nf;
        out[1] = accum[1]/nf;
    }
}

extern "C" void kernel_launch(void* const* d_in, const int* in_sizes, int n_in,
                              void* d_out, int out_size, void* d_ws, size_t ws_size,
                              hipStream_t stream) {
    const float* pred_cls  = (const float*)d_in[0];
    const float* pred_box  = (const float*)d_in[1];
    const float* gt_boxes  = (const float*)d_in[3];
    const int*   gt_labels = (const int*)d_in[4];
    const unsigned char* mask = (const unsigned char*)d_in[5];
    float* out = (float*)d_out;

    auto need = [](int nc) -> size_t {
        return 256 + (size_t)NB*MM*8 + 2*(size_t)NB*NG*nc*TOPK*8;
    };
    int nchunk = 50;
    if (ws_size < need(50)) nchunk = 25;
    if (ws_size < need(25)) return;     // visible failure rather than corruption

    char* ws = (char*)d_ws;
    float* accum = (float*)ws;                                   // 256 B reserved
    ull* best      = (ull*)(ws + 256);                           // NB*MM ulls
    ull* cost_part = (ull*)(ws + 256 + (size_t)NB*MM*8);
    ull* iou_part  = cost_part + (size_t)NB*NG*nchunk*TOPK;

    hipMemsetAsync(accum, 0, 16, stream);
    hipMemsetAsync(best, 0xFF, (size_t)NB*MM*8, stream);

    k_cost <<<NB*nchunk, 256, 0, stream>>>(pred_cls, pred_box, gt_boxes, gt_labels,
                                           mask, cost_part, iou_part, accum, nchunk);
    k_merge<<<NB*NG/4,   256, 0, stream>>>(cost_part, iou_part, best, nchunk);
    k_post <<<NB*MM/256, 256, 0, stream>>>(pred_cls, pred_box, gt_boxes, gt_labels,
                                           mask, best, accum);
    k_final<<<1, 64, 0, stream>>>(accum, out);
}

// Round 4
// 236.901 us; speedup vs baseline: 1.5296x; 1.0313x over previous
//
#include <hip/hip_runtime.h>
#include <cstdint>
#include <cstddef>

#define NB 16
#define SIDE 160
#define MM (SIDE*SIDE)      // 25600 anchors
#define NC 80
#define NG 32
#define TOPK 10
#define REGW 3.0f
#define INVC 1e9f

using ull = unsigned long long;

__device__ __forceinline__ unsigned f2sort(float f) {
    unsigned b = __float_as_uint(f);
    return b ^ ((unsigned)((int)b >> 31) | 0x80000000u);
}
__device__ __forceinline__ float sort2f(unsigned s) {
    unsigned b = s ^ ((s & 0x80000000u) ? 0x80000000u : 0xFFFFFFFFu);
    return __uint_as_float(b);
}
__device__ __forceinline__ ull shflx64(ull v, int m) {
    int lo = __shfl_xor((int)(unsigned)v, m);
    int hi = __shfl_xor((int)(unsigned)(v >> 32), m);
    return ((ull)(unsigned)hi << 32) | (unsigned)lo;
}
__device__ __forceinline__ float rcpf(float x) { return __builtin_amdgcn_rcpf(x); }

__device__ __forceinline__ float f_bg(float x) {
    float e  = __expf(-fabsf(x));
    float rc = rcpf(1.f + e);
    float p  = (x >= 0.f) ? rc : e*rc;            // sigmoid(x)
    float sp = fmaxf(x, 0.f) + __logf(1.f + e);   // softplus(x)
    return sp*p*p*0.75f;
}
__device__ __forceinline__ float f_fg(float x) {
    float e  = __expf(-fabsf(x));
    float rc = rcpf(1.f + e);
    float p  = (x >= 0.f) ? rc : e*rc;
    float sp = fmaxf(x, 0.f) + __logf(1.f + e);
    float om = 1.f - p;
    return (sp - x)*om*om*0.25f;                  // softplus(-x)*(1-p)^2*alpha
}

// ---------------- valid anchors: inside ANY gt of the image -----------------
__global__ __launch_bounds__(256) void k_valid(const float* __restrict__ anchors,
                                               const float* __restrict__ gt_boxes,
                                               unsigned char* __restrict__ valid) {
    int i = blockIdx.x * 256 + threadIdx.x;          // i in [0, NB*MM)
    int b = i / MM, m = i % MM;
    float ax = anchors[2*m], ay = anchors[2*m+1];
    const float* gb = gt_boxes + b*NG*4;
    unsigned char v = 0;
    for (int g = 0; g < NG; ++g) {
        float x1 = gb[4*g], y1 = gb[4*g+1], x2 = gb[4*g+2], y2 = gb[4*g+3];
        float d = fminf(fminf(ax-x1, ay-y1), fminf(x2-ax, y2-ay));
        v |= (d > 0.f) ? 1 : 0;
    }
    valid[i] = v;
}

// ---------------- background focal sum: pure streaming ----------------------
__global__ __launch_bounds__(256) void k_bg(const float* __restrict__ pred_cls,
                                            const unsigned char* __restrict__ mask,
                                            float* __restrict__ accum) {
    const unsigned total4 = (unsigned)NB*MM*NC/4;   // 8,192,000 float4s
    unsigned stride = gridDim.x * blockDim.x;
    float acc = 0.f;
    for (unsigned i4 = blockIdx.x*blockDim.x + threadIdx.x; i4 < total4; i4 += stride) {
        float4 v = ((const float4*)pred_cls)[i4];
        unsigned row = i4 / 20;                     // anchor row (20 float4 per row)
        if (!mask[row])
            acc += f_bg(v.x) + f_bg(v.y) + f_bg(v.z) + f_bg(v.w);
    }
    for (int o = 32; o; o >>= 1) acc += __shfl_down(acc, o);
    __shared__ float sw[4];
    int ln = threadIdx.x & 63, wv = threadIdx.x >> 6;
    if (ln == 0) sw[wv] = acc;
    __syncthreads();
    if (threadIdx.x == 0) atomicAdd(&accum[0], sw[0]+sw[1]+sw[2]+sw[3]);
}

// ============ per-(b,chunk): cost/iou top-10 partials (16 threads/gt) =======
__global__ __launch_bounds__(512, 8) void k_cost(
    const float* __restrict__ pred_cls, const float* __restrict__ pred_box,
    const float* __restrict__ gt_boxes, const int* __restrict__ gt_labels,
    const unsigned char* __restrict__ valid,
    ull* __restrict__ cost_part, ull* __restrict__ iou_part, int nchunk)
{
    __shared__ float s_cls[64*84];      // 21,504 B, stride 84 -> 16B-aligned rows
    __shared__ float4 s_box[64];
    __shared__ unsigned char s_vld[64];
    __shared__ float s_gtb[128];
    __shared__ int s_lab[32];

    int blk = blockIdx.x;
    int b = blk / nchunk, chunk = blk - b*nchunk;
    int A = MM / nchunk;                // 512 (nchunk=50) or 1024 (25)
    int nsub = A >> 6;
    int tid = threadIdx.x;
    int g = tid >> 4, j = tid & 15;

    if (tid < 128) s_gtb[tid] = gt_boxes[b*NG*4 + tid];
    if (tid < 32)  s_lab[tid] = gt_labels[b*NG + tid];
    __syncthreads();

    float gx1 = s_gtb[g*4+0], gy1 = s_gtb[g*4+1];
    float gx2 = s_gtb[g*4+2], gy2 = s_gtb[g*4+3];
    int   lab = s_lab[g];
    float garea = (gx2-gx1)*(gy2-gy1);

    ull lc[TOPK], li[TOPK];
    #pragma unroll
    for (int t = 0; t < TOPK; ++t) { lc[t] = ~0ull; li[t] = ~0ull; }

    int m0 = chunk * A;
    for (int s = 0; s < nsub; ++s) {
        int mbase = m0 + s*64;
        size_t gbase = (size_t)b*MM + mbase;
        __syncthreads();                 // prior subtile's LDS reads done
        if (tid < 64) {
            s_box[tid] = ((const float4*)pred_box)[gbase + tid];
            s_vld[tid] = valid[gbase + tid];
        }
        const float4* gcls = (const float4*)(pred_cls + gbase*NC);
        #pragma unroll
        for (int q = 0; q < 3; ++q) {    // 1280 float4s over 512 threads
            int idx = tid + 512*q;
            if (idx < 1280) {
                float4 v = gcls[idx];
                int a = idx / 20, c4 = (idx - a*20)*4;
                *(float4*)&s_cls[a*84 + c4] = v;
            }
        }
        __syncthreads();                 // staged
        #pragma unroll
        for (int k = 0; k < 4; ++k) {
            int a = j + 16*k;
            unsigned m = (unsigned)(mbase + a);
            float4 pb = s_box[a];
            float iw = fmaxf(fminf(gx2, pb.z) - fmaxf(gx1, pb.x), 0.f);
            float ih = fmaxf(fminf(gy2, pb.w) - fmaxf(gy1, pb.y), 0.f);
            float inter = iw*ih;
            float pa = (pb.z-pb.x)*(pb.w-pb.y);
            float uni = garea + pa - inter;
            float iou = inter * rcpf(fmaxf(uni, 1e-8f));
            float l = s_cls[a*84 + lab];
            float e  = __expf(-fabsf(l));
            float rc = rcpf(1.f + e);
            float sg = (l >= 0.f) ? rc : e*rc;
            float sp_pos = fmaxf(l, 0.f) + __logf(1.f + e);
            float sp_neg = sp_pos - l;
            float bce = iou*sp_neg + (1.f-iou)*sp_pos;
            float dd = iou - sg;
            float cost = bce*dd*dd - REGW*__logf(iou + 1e-8f);
            if (!s_vld[a]) cost = INVC;
            ull ck = ((ull)f2sort(cost) << 32) | m;
            if (ck < lc[TOPK-1]) {
                ull cur = ck;
                #pragma unroll
                for (int t = 0; t < TOPK; ++t) {
                    ull mn = lc[t] < cur ? lc[t] : cur;
                    ull mx = lc[t] < cur ? cur : lc[t];
                    lc[t] = mn; cur = mx;
                }
            }
            ull ik = ((ull)(~f2sort(iou)) << 32) | m;
            if (ik < li[TOPK-1]) {
                ull cur = ik;
                #pragma unroll
                for (int t = 0; t < TOPK; ++t) {
                    ull mn = li[t] < cur ? li[t] : cur;
                    ull mx = li[t] < cur ? cur : li[t];
                    li[t] = mn; cur = mx;
                }
            }
        }
    }
    // ---- merge per-thread lists within the 16-lane group; j==0 writes ----
    size_t pbase = ((size_t)(b*NG + g)*nchunk + chunk)*TOPK;
    #pragma unroll
    for (int r = 0; r < TOPK; ++r) {
        ull h = lc[0];
        { ull o=shflx64(h,1); h=o<h?o:h; o=shflx64(h,2); h=o<h?o:h;
          o=shflx64(h,4); h=o<h?o:h; o=shflx64(h,8); h=o<h?o:h; }
        if (lc[0] == h) {
            #pragma unroll
            for (int t = 0; t < TOPK-1; ++t) lc[t] = lc[t+1];
            lc[TOPK-1] = ~0ull;
        }
        if (j == 0) cost_part[pbase + r] = h;
    }
    #pragma unroll
    for (int r = 0; r < TOPK; ++r) {
        ull h = li[0];
        { ull o=shflx64(h,1); h=o<h?o:h; o=shflx64(h,2); h=o<h?o:h;
          o=shflx64(h,4); h=o<h?o:h; o=shflx64(h,8); h=o<h?o:h; }
        if (li[0] == h) {
            #pragma unroll
            for (int t = 0; t < TOPK-1; ++t) li[t] = li[t+1];
            li[TOPK-1] = ~0ull;
        }
        if (j == 0) iou_part[pbase + r] = h;
    }
}

// ============ per-(b,g) wave: dyn_k + global top-10 + scatter ===============
__global__ __launch_bounds__(256) void k_merge(
    const ull* __restrict__ cost_part, const ull* __restrict__ iou_part,
    ull* __restrict__ best, int nchunk)
{
    int lane = threadIdx.x & 63, wv = threadIdx.x >> 6;
    int bg = blockIdx.x*4 + wv;
    int b = bg >> 5, g = bg & (NG-1);
    int nent = nchunk * TOPK;           // <= 500
    size_t base = (size_t)bg * nent;

    ull l10[TOPK];
    // ---- iou partials -> dyn_k ----
    #pragma unroll
    for (int t = 0; t < TOPK; ++t) l10[t] = ~0ull;
    #pragma unroll
    for (int q = 0; q < 8; ++q) {
        int e = lane + 64*q;
        ull v = (e < nent) ? iou_part[base + e] : ~0ull;
        if (v < l10[TOPK-1]) {
            ull cur = v;
            #pragma unroll
            for (int t = 0; t < TOPK; ++t) { ull mn=l10[t]<cur?l10[t]:cur; ull mx=l10[t]<cur?cur:l10[t]; l10[t]=mn; cur=mx; }
        }
    }
    float isum = 0.f;
    #pragma unroll
    for (int r = 0; r < TOPK; ++r) {
        ull h = l10[0];
        #pragma unroll
        for (int mlt = 1; mlt < 64; mlt <<= 1) { ull o = shflx64(h, mlt); h = o<h?o:h; }
        if (l10[0] == h) {
            #pragma unroll
            for (int t = 0; t < TOPK-1; ++t) l10[t] = l10[t+1];
            l10[TOPK-1] = ~0ull;
        }
        isum += sort2f(~(unsigned)(h >> 32));
    }
    int dynk = (int)isum; if (dynk < 1) dynk = 1;

    // ---- cost partials -> top-10, scatter rank<dynk ----
    #pragma unroll
    for (int t = 0; t < TOPK; ++t) l10[t] = ~0ull;
    #pragma unroll
    for (int q = 0; q < 8; ++q) {
        int e = lane + 64*q;
        ull v = (e < nent) ? cost_part[base + e] : ~0ull;
        if (v < l10[TOPK-1]) {
            ull cur = v;
            #pragma unroll
            for (int t = 0; t < TOPK; ++t) { ull mn=l10[t]<cur?l10[t]:cur; ull mx=l10[t]<cur?cur:l10[t]; l10[t]=mn; cur=mx; }
        }
    }
    ull mykey = ~0ull;
    #pragma unroll
    for (int r = 0; r < TOPK; ++r) {
        ull h = l10[0];
        #pragma unroll
        for (int mlt = 1; mlt < 64; mlt <<= 1) { ull o = shflx64(h, mlt); h = o<h?o:h; }
        if (l10[0] == h) {
            #pragma unroll
            for (int t = 0; t < TOPK-1; ++t) l10[t] = l10[t+1];
            l10[TOPK-1] = ~0ull;
        }
        if (lane == r) mykey = h;
    }
    if (lane < dynk) {
        unsigned m  = (unsigned)mykey;
        unsigned cb = (unsigned)(mykey >> 32);
        atomicMin(&best[(size_t)b*MM + m], ((ull)cb << 32) | (unsigned)g);
    }
}

// ============ per-anchor: giou + fg count + focal fg correction =============
__global__ __launch_bounds__(256) void k_post(
    const float* __restrict__ pred_cls, const float* __restrict__ pred_box,
    const float* __restrict__ gt_boxes, const int* __restrict__ gt_labels,
    const unsigned char* __restrict__ mask, const ull* __restrict__ best,
    float* __restrict__ accum)
{
    int i = blockIdx.x*256 + threadIdx.x;   // exact grid
    int b = i / MM;
    ull key = best[i];
    float cls_c = 0.f, giou_c = 0.f, cnt = 0.f;
    if (key != ~0ull) {
        int g = (int)(key & 0xFFFFFFFFull);
        int bgi = b*NG + g;
        float4 pb = *(const float4*)(pred_box + (size_t)i*4);
        float gx1 = gt_boxes[bgi*4],   gy1 = gt_boxes[bgi*4+1];
        float gx2 = gt_boxes[bgi*4+2], gy2 = gt_boxes[bgi*4+3];
        float iw = fmaxf(fminf(pb.z,gx2) - fmaxf(pb.x,gx1), 0.f);
        float ih = fmaxf(fminf(pb.w,gy2) - fmaxf(pb.y,gy1), 0.f);
        float inter = iw*ih;
        float a1 = fmaxf(pb.z-pb.x,0.f)*fmaxf(pb.w-pb.y,0.f);
        float a2 = fmaxf(gx2-gx1,0.f)*fmaxf(gy2-gy1,0.f);
        float uni = a1 + a2 - inter;
        float iou = inter / fmaxf(uni, 1e-7f);
        float cw = fmaxf(fmaxf(pb.z,gx2) - fminf(pb.x,gx1), 0.f);
        float ch = fmaxf(fmaxf(pb.w,gy2) - fminf(pb.y,gy1), 0.f);
        float ca = fmaxf(cw*ch, 1e-7f);
        float giou = iou - (ca - uni)/ca;
        giou_c = 1.f - giou;
        cnt = 1.f;
        if (!mask[i]) {
            int lab = gt_labels[bgi];
            float x = pred_cls[(size_t)i*NC + lab];
            cls_c = f_fg(x) - f_bg(x);      // replace bg term with fg term
        }
    }
    for (int o = 32; o; o >>= 1) {
        cls_c  += __shfl_down(cls_c, o);
        giou_c += __shfl_down(giou_c, o);
        cnt    += __shfl_down(cnt, o);
    }
    __shared__ float sc[4], sg_[4], sn[4];
    int ln = threadIdx.x & 63, wv = threadIdx.x >> 6;
    if (ln == 0) { sc[wv] = cls_c; sg_[wv] = giou_c; sn[wv] = cnt; }
    __syncthreads();
    if (threadIdx.x == 0) {
        atomicAdd(&accum[0], sc[0]+sc[1]+sc[2]+sc[3]);
        float gtot = sg_[0]+sg_[1]+sg_[2]+sg_[3];
        float ntot = sn[0]+sn[1]+sn[2]+sn[3];
        if (gtot != 0.f || ntot != 0.f) {
            atomicAdd(&accum[1], gtot);
            atomicAdd(&accum[2], ntot);
        }
    }
}

__global__ void k_final(const float* __restrict__ accum, float* __restrict__ out) {
    if (threadIdx.x == 0) {
        float nf = fmaxf(accum[2], 1.f);
        out[0] = accum[0]/nf;
        out[1] = accum[1]/nf;
    }
}

extern "C" void kernel_launch(void* const* d_in, const int* in_sizes, int n_in,
                              void* d_out, int out_size, void* d_ws, size_t ws_size,
                              hipStream_t stream) {
    const float* pred_cls  = (const float*)d_in[0];
    const float* pred_box  = (const float*)d_in[1];
    const float* anchors   = (const float*)d_in[2];
    const float* gt_boxes  = (const float*)d_in[3];
    const int*   gt_labels = (const int*)d_in[4];
    const unsigned char* mask = (const unsigned char*)d_in[5];
    float* out = (float*)d_out;

    auto need = [](int nc) -> size_t {
        return 256 + (size_t)NB*MM*8 + 2*(size_t)NB*NG*nc*TOPK*8;
    };
    int nchunk = 50;
    if (ws_size < need(50)) nchunk = 25;
    if (ws_size < need(25)) return;     // visible failure rather than corruption

    char* ws = (char*)d_ws;
    float* accum = (float*)ws;                                   // 256 B reserved
    ull* best      = (ull*)(ws + 256);                           // NB*MM ulls
    unsigned char* valid = (unsigned char*)best;                 // aliases best (dead by memset time)
    ull* cost_part = (ull*)(ws + 256 + (size_t)NB*MM*8);
    ull* iou_part  = cost_part + (size_t)NB*NG*nchunk*TOPK;

    hipMemsetAsync(accum, 0, 16, stream);

    k_valid<<<NB*MM/256, 256, 0, stream>>>(anchors, gt_boxes, valid);
    k_bg   <<<2048, 256, 0, stream>>>(pred_cls, mask, accum);    // also warms L3 for k_cost
    k_cost <<<NB*nchunk, 512, 0, stream>>>(pred_cls, pred_box, gt_boxes, gt_labels,
                                           valid, cost_part, iou_part, nchunk);
    hipMemsetAsync(best, 0xFF, (size_t)NB*MM*8, stream);         // valid is dead now
    k_merge<<<NB*NG/4,   256, 0, stream>>>(cost_part, iou_part, best, nchunk);
    k_post <<<NB*MM/256, 256, 0, stream>>>(pred_cls, pred_box, gt_boxes, gt_labels,
                                           mask, best, accum);
    k_final<<<1, 64, 0, stream>>>(accum, out);
}

// Round 5
// 179.195 us; speedup vs baseline: 2.0222x; 1.3220x over previous
//
#include <hip/hip_runtime.h>
#include <cstdint>
#include <cstddef>

#define NB 16
#define SIDE 160
#define MM (SIDE*SIDE)      // 25600 anchors
#define NC 80
#define NG 32
#define TOPK 10
#define REGW 3.0f
#define INVC 1e9f

using ull = unsigned long long;

__device__ __forceinline__ unsigned f2sort(float f) {
    unsigned b = __float_as_uint(f);
    return b ^ ((unsigned)((int)b >> 31) | 0x80000000u);
}
__device__ __forceinline__ float rcpf(float x) { return __builtin_amdgcn_rcpf(x); }

// fast variants (hot path, selection only)
__device__ __forceinline__ float f_bg(float x) {
    float e  = __expf(-fabsf(x));
    float rc = rcpf(1.f + e);
    float p  = (x >= 0.f) ? rc : e*rc;            // sigmoid(x)
    float sp = fmaxf(x, 0.f) + __logf(1.f + e);   // softplus(x)
    return sp*p*p*0.75f;
}
__device__ __forceinline__ float f_fg(float x) {
    float e  = __expf(-fabsf(x));
    float rc = rcpf(1.f + e);
    float p  = (x >= 0.f) ? rc : e*rc;
    float sp = fmaxf(x, 0.f) + __logf(1.f + e);
    float om = 1.f - p;
    return (sp - x)*om*om*0.25f;                  // softplus(-x)*(1-p)^2*alpha
}

// ---------------- valid anchors: inside ANY gt of the image -----------------
__global__ __launch_bounds__(256) void k_valid(const float* __restrict__ anchors,
                                               const float* __restrict__ gt_boxes,
                                               unsigned char* __restrict__ valid) {
    int i = blockIdx.x * 256 + threadIdx.x;          // i in [0, NB*MM)
    int b = i / MM, m = i % MM;
    float ax = anchors[2*m], ay = anchors[2*m+1];
    const float* gb = gt_boxes + b*NG*4;
    unsigned char v = 0;
    for (int g = 0; g < NG; ++g) {
        float x1 = gb[4*g], y1 = gb[4*g+1], x2 = gb[4*g+2], y2 = gb[4*g+3];
        float d = fminf(fminf(ax-x1, ay-y1), fminf(x2-ax, y2-ay));
        v |= (d > 0.f) ? 1 : 0;
    }
    valid[i] = v;
}

// ===== fused: bg-focal + cost/iou packed top-10 partials (16 thr/gt) ========
__global__ __launch_bounds__(512, 4) void k_cost(
    const float* __restrict__ pred_cls, const float* __restrict__ pred_box,
    const float* __restrict__ gt_boxes, const int* __restrict__ gt_labels,
    const unsigned char* __restrict__ valid, const unsigned char* __restrict__ mask,
    unsigned* __restrict__ cost_part, unsigned* __restrict__ iou_part,
    float* __restrict__ accum, int nchunk)
{
    __shared__ float s_cls[64*33];      // label-slot columns only: 8448 B
    __shared__ float4 s_box[64];
    __shared__ unsigned char s_vld[64];
    __shared__ float s_gtb[128];
    __shared__ int s_lab[32];
    __shared__ int s_slot[80];
    __shared__ float s_red[8];

    int blk = blockIdx.x;
    int b = blk / nchunk, chunk = blk - b*nchunk;
    int A = MM / nchunk;                // 512 (nchunk=50) or 1024 (25)
    int nsub = A >> 6;
    int tid = threadIdx.x;
    int g = tid >> 4, j = tid & 15;

    if (tid < 128) s_gtb[tid] = gt_boxes[b*NG*4 + tid];
    if (tid < 32)  s_lab[tid] = gt_labels[b*NG + tid];
    if (tid < 80)  s_slot[tid] = 9999;
    __syncthreads();
    if (tid < 32) atomicMin(&s_slot[s_lab[tid]], tid);   // lowest-g slot per class
    __syncthreads();

    float gx1 = s_gtb[g*4+0], gy1 = s_gtb[g*4+1];
    float gx2 = s_gtb[g*4+2], gy2 = s_gtb[g*4+3];
    int slot = s_slot[s_lab[g]];        // < 32 always (own g qualifies)
    float garea = (gx2-gx1)*(gy2-gy1);

    unsigned lc[TOPK], li[TOPK];
    #pragma unroll
    for (int t = 0; t < TOPK; ++t) { lc[t] = 0xFFFFFFFFu; li[t] = 0xFFFFFFFFu; }
    float bgsum = 0.f;

    int m0 = chunk * A;
    for (int s = 0; s < nsub; ++s) {
        int mbase = m0 + s*64;
        size_t gbase = (size_t)b*MM + mbase;
        __syncthreads();                 // prior subtile's LDS reads done
        if (tid < 64) {
            s_box[tid] = ((const float4*)pred_box)[gbase + tid];
            s_vld[tid] = valid[gbase + tid];
        }
        const float4* gcls = (const float4*)(pred_cls + gbase*NC);
        #pragma unroll
        for (int q = 0; q < 3; ++q) {    // 1280 float4s over 512 threads
            int idx = tid + 512*q;
            if (idx < 1280) {
                float4 v = gcls[idx];
                int a = idx / 20, c0 = (idx - a*20)*4;
                int t0 = s_slot[c0], t1 = s_slot[c0+1], t2 = s_slot[c0+2], t3 = s_slot[c0+3];
                if (t0 < 64) s_cls[a*33 + t0] = v.x;
                if (t1 < 64) s_cls[a*33 + t1] = v.y;
                if (t2 < 64) s_cls[a*33 + t2] = v.z;
                if (t3 < 64) s_cls[a*33 + t3] = v.w;
                if (!mask[gbase + a])    // bg focal from staging registers
                    bgsum += f_bg(v.x) + f_bg(v.y) + f_bg(v.z) + f_bg(v.w);
            }
        }
        __syncthreads();                 // staged
        #pragma unroll
        for (int k = 0; k < 4; ++k) {
            int a = j + 16*k;
            unsigned m = (unsigned)(mbase + a);     // < 25600, fits 15 bits
            float4 pb = s_box[a];
            float iw = fmaxf(fminf(gx2, pb.z) - fmaxf(gx1, pb.x), 0.f);
            float ih = fmaxf(fminf(gy2, pb.w) - fmaxf(gy1, pb.y), 0.f);
            float inter = iw*ih;
            float pa = (pb.z-pb.x)*(pb.w-pb.y);
            float uni = garea + pa - inter;
            float iou = inter * rcpf(fmaxf(uni, 1e-8f));
            float l = s_cls[a*33 + slot];
            float e  = __expf(-fabsf(l));
            float rc = rcpf(1.f + e);
            float sg = (l >= 0.f) ? rc : e*rc;
            float sp_pos = fmaxf(l, 0.f) + __logf(1.f + e);
            float sp_neg = sp_pos - l;
            float bce = iou*sp_neg + (1.f-iou)*sp_pos;
            float dd = iou - sg;
            float cost = bce*dd*dd - REGW*__logf(iou + 1e-8f);
            if (!s_vld[a]) cost = INVC;
            // packed 17-bit key + 15-bit idx; branchless min/max bubble
            unsigned cur = (f2sort(cost) & 0xFFFF8000u) | m;
            #pragma unroll
            for (int t = 0; t < TOPK; ++t) {
                unsigned mn = min(lc[t], cur), mx = max(lc[t], cur);
                lc[t] = mn; cur = mx;
            }
            cur = (~f2sort(iou) & 0xFFFF8000u) | m;
            #pragma unroll
            for (int t = 0; t < TOPK; ++t) {
                unsigned mn = min(li[t], cur), mx = max(li[t], cur);
                li[t] = mn; cur = mx;
            }
        }
    }
    // ---- merge per-thread lists within the 16-lane group; j==0 writes ----
    size_t pbase = ((size_t)(b*NG + g)*nchunk + chunk)*TOPK;
    #pragma unroll
    for (int r = 0; r < TOPK; ++r) {
        unsigned h = lc[0];
        h = min(h, (unsigned)__shfl_xor((int)h, 1));
        h = min(h, (unsigned)__shfl_xor((int)h, 2));
        h = min(h, (unsigned)__shfl_xor((int)h, 4));
        h = min(h, (unsigned)__shfl_xor((int)h, 8));
        if (lc[0] == h) {
            #pragma unroll
            for (int t = 0; t < TOPK-1; ++t) lc[t] = lc[t+1];
            lc[TOPK-1] = 0xFFFFFFFFu;
        }
        if (j == 0) cost_part[pbase + r] = h;
    }
    #pragma unroll
    for (int r = 0; r < TOPK; ++r) {
        unsigned h = li[0];
        h = min(h, (unsigned)__shfl_xor((int)h, 1));
        h = min(h, (unsigned)__shfl_xor((int)h, 2));
        h = min(h, (unsigned)__shfl_xor((int)h, 4));
        h = min(h, (unsigned)__shfl_xor((int)h, 8));
        if (li[0] == h) {
            #pragma unroll
            for (int t = 0; t < TOPK-1; ++t) li[t] = li[t+1];
            li[TOPK-1] = 0xFFFFFFFFu;
        }
        if (j == 0) iou_part[pbase + r] = h;
    }
    // ---- block reduce bg focal sum ----
    for (int o = 32; o; o >>= 1) bgsum += __shfl_down(bgsum, o);
    int ln = tid & 63, wv = tid >> 6;
    if (ln == 0) s_red[wv] = bgsum;
    __syncthreads();
    if (tid == 0) {
        float sum = 0.f;
        #pragma unroll
        for (int w = 0; w < 8; ++w) sum += s_red[w];
        atomicAdd(&accum[0], sum);
    }
}

// === per-(b,g) wave: merge partials; exact dyn_k + exact cost; scatter ======
__global__ __launch_bounds__(256) void k_merge(
    const unsigned* __restrict__ cost_part, const unsigned* __restrict__ iou_part,
    const float* __restrict__ pred_cls, const float* __restrict__ pred_box,
    const float* __restrict__ gt_boxes, const int* __restrict__ gt_labels,
    const unsigned char* __restrict__ valid,
    ull* __restrict__ best, int nchunk)
{
    int lane = threadIdx.x & 63, wv = threadIdx.x >> 6;
    int bg = blockIdx.x*4 + wv;
    int b = bg >> 5, g = bg & (NG-1);
    int nent = nchunk * TOPK;           // 500 or 250 (>= 10 real entries)
    size_t base = (size_t)bg * nent;

    float gx1 = gt_boxes[bg*4+0], gy1 = gt_boxes[bg*4+1];
    float gx2 = gt_boxes[bg*4+2], gy2 = gt_boxes[bg*4+3];
    int   lab = gt_labels[bg];
    float garea = (gx2-gx1)*(gy2-gy1);

    unsigned l10[TOPK];
    // ---- iou partials -> top-10 keys ----
    #pragma unroll
    for (int t = 0; t < TOPK; ++t) l10[t] = 0xFFFFFFFFu;
    for (int q = 0; q*64 < nent; ++q) {
        int e = lane + 64*q;
        unsigned cur = (e < nent) ? iou_part[base + e] : 0xFFFFFFFFu;
        #pragma unroll
        for (int t = 0; t < TOPK; ++t) {
            unsigned mn = min(l10[t], cur), mx = max(l10[t], cur);
            l10[t] = mn; cur = mx;
        }
    }
    unsigned ioukey = 0xFFFFFFFFu;
    #pragma unroll
    for (int r = 0; r < TOPK; ++r) {
        unsigned h = l10[0];
        #pragma unroll
        for (int mlt = 1; mlt < 64; mlt <<= 1)
            h = min(h, (unsigned)__shfl_xor((int)h, mlt));
        if (l10[0] == h) {
            #pragma unroll
            for (int t = 0; t < TOPK-1; ++t) l10[t] = l10[t+1];
            l10[TOPK-1] = 0xFFFFFFFFu;
        }
        if (lane == r) ioukey = h;
    }
    // exact iou recompute for lanes 0..9 -> exact dyn_k
    float myiou = 0.f;
    if (lane < TOPK) {
        int m = (int)(ioukey & 0x7FFFu);
        float4 pb = ((const float4*)pred_box)[(size_t)b*MM + m];
        float iw = fmaxf(fminf(gx2, pb.z) - fmaxf(gx1, pb.x), 0.f);
        float ih = fmaxf(fminf(gy2, pb.w) - fmaxf(gy1, pb.y), 0.f);
        float inter = iw*ih;
        float pa = (pb.z-pb.x)*(pb.w-pb.y);
        float uni = garea + pa - inter;
        myiou = inter / fmaxf(uni, 1e-8f);
    }
    #pragma unroll
    for (int mlt = 1; mlt < 64; mlt <<= 1) myiou += __shfl_xor(myiou, mlt);
    int dynk = (int)myiou; if (dynk < 1) dynk = 1;

    // ---- cost partials -> top-10 keys ----
    #pragma unroll
    for (int t = 0; t < TOPK; ++t) l10[t] = 0xFFFFFFFFu;
    for (int q = 0; q*64 < nent; ++q) {
        int e = lane + 64*q;
        unsigned cur = (e < nent) ? cost_part[base + e] : 0xFFFFFFFFu;
        #pragma unroll
        for (int t = 0; t < TOPK; ++t) {
            unsigned mn = min(l10[t], cur), mx = max(l10[t], cur);
            l10[t] = mn; cur = mx;
        }
    }
    unsigned costkey = 0xFFFFFFFFu;
    #pragma unroll
    for (int r = 0; r < TOPK; ++r) {
        unsigned h = l10[0];
        #pragma unroll
        for (int mlt = 1; mlt < 64; mlt <<= 1)
            h = min(h, (unsigned)__shfl_xor((int)h, mlt));
        if (l10[0] == h) {
            #pragma unroll
            for (int t = 0; t < TOPK-1; ++t) l10[t] = l10[t+1];
            l10[TOPK-1] = 0xFFFFFFFFu;
        }
        if (lane == r) costkey = h;
    }
    // exact cost recompute + scatter for lanes < dynk (dynk <= 10)
    if (lane < dynk) {
        unsigned m = costkey & 0x7FFFu;
        size_t gi = (size_t)b*MM + m;
        float cost;
        if (!valid[gi]) {
            cost = INVC;
        } else {
            float4 pb = ((const float4*)pred_box)[gi];
            float iw = fmaxf(fminf(gx2, pb.z) - fmaxf(gx1, pb.x), 0.f);
            float ih = fmaxf(fminf(gy2, pb.w) - fmaxf(gy1, pb.y), 0.f);
            float inter = iw*ih;
            float pa = (pb.z-pb.x)*(pb.w-pb.y);
            float uni = garea + pa - inter;
            float iou = inter / fmaxf(uni, 1e-8f);
            float l = pred_cls[gi*NC + lab];
            float e  = expf(-fabsf(l));           // precise libm, cold path
            float p  = 1.f/(1.f + e);
            float sg = (l >= 0.f) ? p : e*p;
            float sp_pos = fmaxf(l, 0.f) + log1pf(e);
            float sp_neg = sp_pos - l;
            float bce = iou*sp_neg + (1.f-iou)*sp_pos;
            float dd = iou - sg;
            cost = bce*dd*dd - REGW*logf(iou + 1e-8f);
        }
        atomicMin(&best[(size_t)b*MM + m], ((ull)f2sort(cost) << 32) | (unsigned)g);
    }
}

// ============ per-anchor: giou + fg count + focal fg correction =============
__global__ __launch_bounds__(256) void k_post(
    const float* __restrict__ pred_cls, const float* __restrict__ pred_box,
    const float* __restrict__ gt_boxes, const int* __restrict__ gt_labels,
    const unsigned char* __restrict__ mask, const ull* __restrict__ best,
    float* __restrict__ accum)
{
    int i = blockIdx.x*256 + threadIdx.x;   // exact grid
    int b = i / MM;
    ull key = best[i];
    float cls_c = 0.f, giou_c = 0.f, cnt = 0.f;
    if (key != ~0ull) {
        int g = (int)(key & 0xFFFFFFFFull);
        int bgi = b*NG + g;
        float4 pb = *(const float4*)(pred_box + (size_t)i*4);
        float gx1 = gt_boxes[bgi*4],   gy1 = gt_boxes[bgi*4+1];
        float gx2 = gt_boxes[bgi*4+2], gy2 = gt_boxes[bgi*4+3];
        float iw = fmaxf(fminf(pb.z,gx2) - fmaxf(pb.x,gx1), 0.f);
        float ih = fmaxf(fminf(pb.w,gy2) - fmaxf(pb.y,gy1), 0.f);
        float inter = iw*ih;
        float a1 = fmaxf(pb.z-pb.x,0.f)*fmaxf(pb.w-pb.y,0.f);
        float a2 = fmaxf(gx2-gx1,0.f)*fmaxf(gy2-gy1,0.f);
        float uni = a1 + a2 - inter;
        float iou = inter / fmaxf(uni, 1e-7f);
        float cw = fmaxf(fmaxf(pb.z,gx2) - fminf(pb.x,gx1), 0.f);
        float ch = fmaxf(fmaxf(pb.w,gy2) - fminf(pb.y,gy1), 0.f);
        float ca = fmaxf(cw*ch, 1e-7f);
        float giou = iou - (ca - uni)/ca;
        giou_c = 1.f - giou;
        cnt = 1.f;
        if (!mask[i]) {
            int lab = gt_labels[bgi];
            float x = pred_cls[(size_t)i*NC + lab];
            cls_c = f_fg(x) - f_bg(x);      // replace bg term with fg term (same f_bg as k_cost)
        }
    }
    for (int o = 32; o; o >>= 1) {
        cls_c  += __shfl_down(cls_c, o);
        giou_c += __shfl_down(giou_c, o);
        cnt    += __shfl_down(cnt, o);
    }
    __shared__ float sc[4], sg_[4], sn[4];
    int ln = threadIdx.x & 63, wv = threadIdx.x >> 6;
    if (ln == 0) { sc[wv] = cls_c; sg_[wv] = giou_c; sn[wv] = cnt; }
    __syncthreads();
    if (threadIdx.x == 0) {
        atomicAdd(&accum[0], sc[0]+sc[1]+sc[2]+sc[3]);
        float gtot = sg_[0]+sg_[1]+sg_[2]+sg_[3];
        float ntot = sn[0]+sn[1]+sn[2]+sn[3];
        if (gtot != 0.f || ntot != 0.f) {
            atomicAdd(&accum[1], gtot);
            atomicAdd(&accum[2], ntot);
        }
    }
}

__global__ void k_final(const float* __restrict__ accum, float* __restrict__ out) {
    if (threadIdx.x == 0) {
        float nf = fmaxf(accum[2], 1.f);
        out[0] = accum[0]/nf;
        out[1] = accum[1]/nf;
    }
}

extern "C" void kernel_launch(void* const* d_in, const int* in_sizes, int n_in,
                              void* d_out, int out_size, void* d_ws, size_t ws_size,
                              hipStream_t stream) {
    const float* pred_cls  = (const float*)d_in[0];
    const float* pred_box  = (const float*)d_in[1];
    const float* anchors   = (const float*)d_in[2];
    const float* gt_boxes  = (const float*)d_in[3];
    const int*   gt_labels = (const int*)d_in[4];
    const unsigned char* mask = (const unsigned char*)d_in[5];
    float* out = (float*)d_out;

    auto need = [](int nc) -> size_t {
        return 256 + (size_t)NB*MM*8 + (size_t)NB*MM + 2*(size_t)NB*NG*nc*TOPK*4;
    };
    int nchunk = 50;
    if (ws_size < need(50)) nchunk = 25;
    if (ws_size < need(25)) return;     // visible failure rather than corruption

    char* ws = (char*)d_ws;
    float* accum = (float*)ws;                                   // 256 B reserved
    ull* best = (ull*)(ws + 256);                                // NB*MM ulls
    unsigned char* valid = (unsigned char*)(ws + 256 + (size_t)NB*MM*8);
    unsigned* cost_part = (unsigned*)(ws + 256 + (size_t)NB*MM*8 + (size_t)NB*MM);
    unsigned* iou_part  = cost_part + (size_t)NB*NG*nchunk*TOPK;

    hipMemsetAsync(accum, 0, 16, stream);
    hipMemsetAsync(best, 0xFF, (size_t)NB*MM*8, stream);

    k_valid<<<NB*MM/256, 256, 0, stream>>>(anchors, gt_boxes, valid);
    k_cost <<<NB*nchunk, 512, 0, stream>>>(pred_cls, pred_box, gt_boxes, gt_labels,
                                           valid, mask, cost_part, iou_part, accum, nchunk);
    k_merge<<<NB*NG/4,   256, 0, stream>>>(cost_part, iou_part, pred_cls, pred_box,
                                           gt_boxes, gt_labels, valid, best, nchunk);
    k_post <<<NB*MM/256, 256, 0, stream>>>(pred_cls, pred_box, gt_boxes, gt_labels,
                                           mask, best, accum);
    k_final<<<1, 64, 0, stream>>>(accum, out);
}

// Round 6
// 169.091 us; speedup vs baseline: 2.1430x; 1.0598x over previous
//
#include <hip/hip_runtime.h>
#include <cstdint>
#include <cstddef>

#define NB 16
#define SIDE 160
#define MM (SIDE*SIDE)      // 25600 anchors
#define NC 80
#define NG 32
#define TOPK 10
#define REGW 3.0f
#define INVC 1e9f

using ull = unsigned long long;

__device__ __forceinline__ unsigned f2sort(float f) {
    unsigned b = __float_as_uint(f);
    return b ^ ((unsigned)((int)b >> 31) | 0x80000000u);
}
__device__ __forceinline__ float rcpf(float x) { return __builtin_amdgcn_rcpf(x); }

// fast variants (hot path, selection + 32M-term sum)
__device__ __forceinline__ float f_bg(float x) {
    float e  = __expf(-fabsf(x));
    float rc = rcpf(1.f + e);
    float p  = (x >= 0.f) ? rc : e*rc;            // sigmoid(x)
    float sp = fmaxf(x, 0.f) + __logf(1.f + e);   // softplus(x)
    return sp*p*p*0.75f;
}
__device__ __forceinline__ float f_fg(float x) {
    float e  = __expf(-fabsf(x));
    float rc = rcpf(1.f + e);
    float p  = (x >= 0.f) ? rc : e*rc;
    float sp = fmaxf(x, 0.f) + __logf(1.f + e);
    float om = 1.f - p;
    return (sp - x)*om*om*0.25f;                  // softplus(-x)*(1-p)^2*alpha
}

// ---------------- valid anchors: inside ANY gt of the image -----------------
__global__ __launch_bounds__(256) void k_valid(const float* __restrict__ anchors,
                                               const float* __restrict__ gt_boxes,
                                               unsigned char* __restrict__ valid) {
    int i = blockIdx.x * 256 + threadIdx.x;          // i in [0, NB*MM)
    int b = i / MM, m = i % MM;
    float ax = anchors[2*m], ay = anchors[2*m+1];
    const float* gb = gt_boxes + b*NG*4;
    unsigned char v = 0;
    for (int g = 0; g < NG; ++g) {
        float x1 = gb[4*g], y1 = gb[4*g+1], x2 = gb[4*g+2], y2 = gb[4*g+3];
        float d = fminf(fminf(ax-x1, ay-y1), fminf(x2-ax, y2-ay));
        v |= (d > 0.f) ? 1 : 0;
    }
    valid[i] = v;
}

// ===== fused, barrier-free: bg-focal stream + cost/iou top-10 (16 thr/gt) ===
// Phase 1 streams the 64-anchor tile (20KB) for the focal sum, warming L1/L2;
// phase 2 gathers the single needed logit per (anchor,gt) straight from cache.
__global__ __launch_bounds__(512, 8) void k_cost(
    const float* __restrict__ pred_cls, const float* __restrict__ pred_box,
    const float* __restrict__ gt_boxes, const int* __restrict__ gt_labels,
    const unsigned char* __restrict__ valid, const unsigned char* __restrict__ mask,
    unsigned* __restrict__ cost_part, unsigned* __restrict__ iou_part,
    float* __restrict__ accum, int nchunk)
{
    __shared__ float s_gtb[128];
    __shared__ int s_lab[32];
    __shared__ float s_red[8];

    int blk = blockIdx.x;
    int b = blk / nchunk, chunk = blk - b*nchunk;
    int A = MM / nchunk;                // 320 (nchunk=80); divisible by 64
    int nsub = A >> 6;
    int tid = threadIdx.x;
    int g = tid >> 4, j = tid & 15;

    if (tid < 128) s_gtb[tid] = gt_boxes[b*NG*4 + tid];
    if (tid < 32)  s_lab[tid] = gt_labels[b*NG + tid];
    __syncthreads();                    // the only barrier before the epilogue

    float gx1 = s_gtb[g*4+0], gy1 = s_gtb[g*4+1];
    float gx2 = s_gtb[g*4+2], gy2 = s_gtb[g*4+3];
    int   lab = s_lab[g];
    float garea = (gx2-gx1)*(gy2-gy1);

    unsigned lc[TOPK], li[TOPK];
    #pragma unroll
    for (int t = 0; t < TOPK; ++t) { lc[t] = 0xFFFFFFFFu; li[t] = 0xFFFFFFFFu; }
    float bgsum = 0.f;

    int m0 = chunk * A;
    for (int s = 0; s < nsub; ++s) {
        int mbase = m0 + s*64;
        size_t gbase = (size_t)b*MM + mbase;
        // ---- phase 1: stream tile (1280 float4) for bg focal; warms cache --
        const float4* gcls = (const float4*)(pred_cls + gbase*NC);
        #pragma unroll
        for (int q = 0; q < 3; ++q) {
            int idx = tid + 512*q;
            if (idx < 1280) {
                float4 v = gcls[idx];
                int a = idx / 20;
                if (!mask[gbase + a])
                    bgsum += f_bg(v.x) + f_bg(v.y) + f_bg(v.z) + f_bg(v.w);
            }
        }
        // ---- phase 2: cost/iou eval, operands gathered from cache ---------
        #pragma unroll
        for (int k = 0; k < 4; ++k) {
            int a = j + 16*k;
            unsigned m = (unsigned)(mbase + a);     // < 25600, fits 15 bits
            size_t gi = gbase + a;
            float4 pb = ((const float4*)pred_box)[gi];   // coalesced per 16-lane group
            float l  = pred_cls[gi*NC + lab];            // L1/L2 hit (phase-1 lines)
            unsigned char vld = valid[gi];
            float iw = fmaxf(fminf(gx2, pb.z) - fmaxf(gx1, pb.x), 0.f);
            float ih = fmaxf(fminf(gy2, pb.w) - fmaxf(gy1, pb.y), 0.f);
            float inter = iw*ih;
            float pa = (pb.z-pb.x)*(pb.w-pb.y);
            float uni = garea + pa - inter;
            float iou = inter * rcpf(fmaxf(uni, 1e-8f));
            float e  = __expf(-fabsf(l));
            float rc = rcpf(1.f + e);
            float sg = (l >= 0.f) ? rc : e*rc;
            float sp_pos = fmaxf(l, 0.f) + __logf(1.f + e);
            float sp_neg = sp_pos - l;
            float bce = iou*sp_neg + (1.f-iou)*sp_pos;
            float dd = iou - sg;
            float cost = bce*dd*dd - REGW*__logf(iou + 1e-8f);
            if (!vld) cost = INVC;
            // packed 17-bit key + 15-bit idx; branchless min/max bubble
            unsigned cur = (f2sort(cost) & 0xFFFF8000u) | m;
            #pragma unroll
            for (int t = 0; t < TOPK; ++t) {
                unsigned mn = min(lc[t], cur), mx = max(lc[t], cur);
                lc[t] = mn; cur = mx;
            }
            cur = (~f2sort(iou) & 0xFFFF8000u) | m;
            #pragma unroll
            for (int t = 0; t < TOPK; ++t) {
                unsigned mn = min(li[t], cur), mx = max(li[t], cur);
                li[t] = mn; cur = mx;
            }
        }
    }
    // ---- merge per-thread lists within the 16-lane group; j==0 writes ----
    size_t pbase = ((size_t)(b*NG + g)*nchunk + chunk)*TOPK;
    #pragma unroll
    for (int r = 0; r < TOPK; ++r) {
        unsigned h = lc[0];
        h = min(h, (unsigned)__shfl_xor((int)h, 1));
        h = min(h, (unsigned)__shfl_xor((int)h, 2));
        h = min(h, (unsigned)__shfl_xor((int)h, 4));
        h = min(h, (unsigned)__shfl_xor((int)h, 8));
        if (lc[0] == h) {
            #pragma unroll
            for (int t = 0; t < TOPK-1; ++t) lc[t] = lc[t+1];
            lc[TOPK-1] = 0xFFFFFFFFu;
        }
        if (j == 0) cost_part[pbase + r] = h;
    }
    #pragma unroll
    for (int r = 0; r < TOPK; ++r) {
        unsigned h = li[0];
        h = min(h, (unsigned)__shfl_xor((int)h, 1));
        h = min(h, (unsigned)__shfl_xor((int)h, 2));
        h = min(h, (unsigned)__shfl_xor((int)h, 4));
        h = min(h, (unsigned)__shfl_xor((int)h, 8));
        if (li[0] == h) {
            #pragma unroll
            for (int t = 0; t < TOPK-1; ++t) li[t] = li[t+1];
            li[TOPK-1] = 0xFFFFFFFFu;
        }
        if (j == 0) iou_part[pbase + r] = h;
    }
    // ---- block reduce bg focal sum ----
    for (int o = 32; o; o >>= 1) bgsum += __shfl_down(bgsum, o);
    int ln = tid & 63, wv = tid >> 6;
    if (ln == 0) s_red[wv] = bgsum;
    __syncthreads();
    if (tid == 0) {
        float sum = 0.f;
        #pragma unroll
        for (int w = 0; w < 8; ++w) sum += s_red[w];
        atomicAdd(&accum[0], sum);
    }
}

// === per-(b,g) wave: merge partials; exact dyn_k + exact cost; scatter ======
__global__ __launch_bounds__(256) void k_merge(
    const unsigned* __restrict__ cost_part, const unsigned* __restrict__ iou_part,
    const float* __restrict__ pred_cls, const float* __restrict__ pred_box,
    const float* __restrict__ gt_boxes, const int* __restrict__ gt_labels,
    const unsigned char* __restrict__ valid,
    ull* __restrict__ best, int nchunk)
{
    int lane = threadIdx.x & 63, wv = threadIdx.x >> 6;
    int bg = blockIdx.x*4 + wv;
    int b = bg >> 5, g = bg & (NG-1);
    int nent = nchunk * TOPK;           // 800 (nchunk=80)
    size_t base = (size_t)bg * nent;

    float gx1 = gt_boxes[bg*4+0], gy1 = gt_boxes[bg*4+1];
    float gx2 = gt_boxes[bg*4+2], gy2 = gt_boxes[bg*4+3];
    int   lab = gt_labels[bg];
    float garea = (gx2-gx1)*(gy2-gy1);

    unsigned l10[TOPK];
    // ---- iou partials -> top-10 keys ----
    #pragma unroll
    for (int t = 0; t < TOPK; ++t) l10[t] = 0xFFFFFFFFu;
    for (int q = 0; q*64 < nent; ++q) {
        int e = lane + 64*q;
        unsigned cur = (e < nent) ? iou_part[base + e] : 0xFFFFFFFFu;
        #pragma unroll
        for (int t = 0; t < TOPK; ++t) {
            unsigned mn = min(l10[t], cur), mx = max(l10[t], cur);
            l10[t] = mn; cur = mx;
        }
    }
    unsigned ioukey = 0xFFFFFFFFu;
    #pragma unroll
    for (int r = 0; r < TOPK; ++r) {
        unsigned h = l10[0];
        #pragma unroll
        for (int mlt = 1; mlt < 64; mlt <<= 1)
            h = min(h, (unsigned)__shfl_xor((int)h, mlt));
        if (l10[0] == h) {
            #pragma unroll
            for (int t = 0; t < TOPK-1; ++t) l10[t] = l10[t+1];
            l10[TOPK-1] = 0xFFFFFFFFu;
        }
        if (lane == r) ioukey = h;
    }
    // exact iou recompute for lanes 0..9 -> exact dyn_k
    float myiou = 0.f;
    if (lane < TOPK) {
        int m = (int)(ioukey & 0x7FFFu);
        float4 pb = ((const float4*)pred_box)[(size_t)b*MM + m];
        float iw = fmaxf(fminf(gx2, pb.z) - fmaxf(gx1, pb.x), 0.f);
        float ih = fmaxf(fminf(gy2, pb.w) - fmaxf(gy1, pb.y), 0.f);
        float inter = iw*ih;
        float pa = (pb.z-pb.x)*(pb.w-pb.y);
        float uni = garea + pa - inter;
        myiou = inter / fmaxf(uni, 1e-8f);
    }
    #pragma unroll
    for (int mlt = 1; mlt < 64; mlt <<= 1) myiou += __shfl_xor(myiou, mlt);
    int dynk = (int)myiou; if (dynk < 1) dynk = 1;

    // ---- cost partials -> top-10 keys ----
    #pragma unroll
    for (int t = 0; t < TOPK; ++t) l10[t] = 0xFFFFFFFFu;
    for (int q = 0; q*64 < nent; ++q) {
        int e = lane + 64*q;
        unsigned cur = (e < nent) ? cost_part[base + e] : 0xFFFFFFFFu;
        #pragma unroll
        for (int t = 0; t < TOPK; ++t) {
            unsigned mn = min(l10[t], cur), mx = max(l10[t], cur);
            l10[t] = mn; cur = mx;
        }
    }
    unsigned costkey = 0xFFFFFFFFu;
    #pragma unroll
    for (int r = 0; r < TOPK; ++r) {
        unsigned h = l10[0];
        #pragma unroll
        for (int mlt = 1; mlt < 64; mlt <<= 1)
            h = min(h, (unsigned)__shfl_xor((int)h, mlt));
        if (l10[0] == h) {
            #pragma unroll
            for (int t = 0; t < TOPK-1; ++t) l10[t] = l10[t+1];
            l10[TOPK-1] = 0xFFFFFFFFu;
        }
        if (lane == r) costkey = h;
    }
    // exact cost recompute + scatter for lanes < dynk (dynk <= 10)
    if (lane < dynk) {
        unsigned m = costkey & 0x7FFFu;
        size_t gi = (size_t)b*MM + m;
        float cost;
        if (!valid[gi]) {
            cost = INVC;
        } else {
            float4 pb = ((const float4*)pred_box)[gi];
            float iw = fmaxf(fminf(gx2, pb.z) - fmaxf(gx1, pb.x), 0.f);
            float ih = fmaxf(fminf(gy2, pb.w) - fmaxf(gy1, pb.y), 0.f);
            float inter = iw*ih;
            float pa = (pb.z-pb.x)*(pb.w-pb.y);
            float uni = garea + pa - inter;
            float iou = inter / fmaxf(uni, 1e-8f);
            float l = pred_cls[gi*NC + lab];
            float e  = expf(-fabsf(l));           // precise libm, cold path
            float p  = 1.f/(1.f + e);
            float sg = (l >= 0.f) ? p : e*p;
            float sp_pos = fmaxf(l, 0.f) + log1pf(e);
            float sp_neg = sp_pos - l;
            float bce = iou*sp_neg + (1.f-iou)*sp_pos;
            float dd = iou - sg;
            cost = bce*dd*dd - REGW*logf(iou + 1e-8f);
        }
        atomicMin(&best[(size_t)b*MM + m], ((ull)f2sort(cost) << 32) | (unsigned)g);
    }
}

// ============ per-anchor: giou + fg count + focal fg correction =============
__global__ __launch_bounds__(256) void k_post(
    const float* __restrict__ pred_cls, const float* __restrict__ pred_box,
    const float* __restrict__ gt_boxes, const int* __restrict__ gt_labels,
    const unsigned char* __restrict__ mask, const ull* __restrict__ best,
    float* __restrict__ accum)
{
    int i = blockIdx.x*256 + threadIdx.x;   // exact grid
    int b = i / MM;
    ull key = best[i];
    float cls_c = 0.f, giou_c = 0.f, cnt = 0.f;
    if (key != ~0ull) {
        int g = (int)(key & 0xFFFFFFFFull);
        int bgi = b*NG + g;
        float4 pb = *(const float4*)(pred_box + (size_t)i*4);
        float gx1 = gt_boxes[bgi*4],   gy1 = gt_boxes[bgi*4+1];
        float gx2 = gt_boxes[bgi*4+2], gy2 = gt_boxes[bgi*4+3];
        float iw = fmaxf(fminf(pb.z,gx2) - fmaxf(pb.x,gx1), 0.f);
        float ih = fmaxf(fminf(pb.w,gy2) - fmaxf(pb.y,gy1), 0.f);
        float inter = iw*ih;
        float a1 = fmaxf(pb.z-pb.x,0.f)*fmaxf(pb.w-pb.y,0.f);
        float a2 = fmaxf(gx2-gx1,0.f)*fmaxf(gy2-gy1,0.f);
        float uni = a1 + a2 - inter;
        float iou = inter / fmaxf(uni, 1e-7f);
        float cw = fmaxf(fmaxf(pb.z,gx2) - fminf(pb.x,gx1), 0.f);
        float ch = fmaxf(fmaxf(pb.w,gy2) - fminf(pb.y,gy1), 0.f);
        float ca = fmaxf(cw*ch, 1e-7f);
        float giou = iou - (ca - uni)/ca;
        giou_c = 1.f - giou;
        cnt = 1.f;
        if (!mask[i]) {
            int lab = gt_labels[bgi];
            float x = pred_cls[(size_t)i*NC + lab];
            cls_c = f_fg(x) - f_bg(x);      // replace bg term with fg term (same f_bg as k_cost)
        }
    }
    for (int o = 32; o; o >>= 1) {
        cls_c  += __shfl_down(cls_c, o);
        giou_c += __shfl_down(giou_c, o);
        cnt    += __shfl_down(cnt, o);
    }
    __shared__ float sc[4], sg_[4], sn[4];
    int ln = threadIdx.x & 63, wv = threadIdx.x >> 6;
    if (ln == 0) { sc[wv] = cls_c; sg_[wv] = giou_c; sn[wv] = cnt; }
    __syncthreads();
    if (threadIdx.x == 0) {
        atomicAdd(&accum[0], sc[0]+sc[1]+sc[2]+sc[3]);
        float gtot = sg_[0]+sg_[1]+sg_[2]+sg_[3];
        float ntot = sn[0]+sn[1]+sn[2]+sn[3];
        if (gtot != 0.f || ntot != 0.f) {
            atomicAdd(&accum[1], gtot);
            atomicAdd(&accum[2], ntot);
        }
    }
}

__global__ void k_final(const float* __restrict__ accum, float* __restrict__ out) {
    if (threadIdx.x == 0) {
        float nf = fmaxf(accum[2], 1.f);
        out[0] = accum[0]/nf;
        out[1] = accum[1]/nf;
    }
}

extern "C" void kernel_launch(void* const* d_in, const int* in_sizes, int n_in,
                              void* d_out, int out_size, void* d_ws, size_t ws_size,
                              hipStream_t stream) {
    const float* pred_cls  = (const float*)d_in[0];
    const float* pred_box  = (const float*)d_in[1];
    const float* anchors   = (const float*)d_in[2];
    const float* gt_boxes  = (const float*)d_in[3];
    const int*   gt_labels = (const int*)d_in[4];
    const unsigned char* mask = (const unsigned char*)d_in[5];
    float* out = (float*)d_out;

    auto need = [](int nc) -> size_t {
        return 256 + (size_t)NB*MM*8 + (size_t)NB*MM + 2*(size_t)NB*NG*nc*TOPK*4;
    };
    int nchunk = 80;                    // 1280 blocks = exactly 5/CU; A=320
    if (ws_size < need(80)) nchunk = 40;
    if (ws_size < need(40)) nchunk = 25;
    if (ws_size < need(25)) return;     // visible failure rather than corruption

    char* ws = (char*)d_ws;
    float* accum = (float*)ws;                                   // 256 B reserved
    ull* best = (ull*)(ws + 256);                                // NB*MM ulls
    unsigned char* valid = (unsigned char*)(ws + 256 + (size_t)NB*MM*8);
    unsigned* cost_part = (unsigned*)(ws + 256 + (size_t)NB*MM*8 + (size_t)NB*MM);
    unsigned* iou_part  = cost_part + (size_t)NB*NG*nchunk*TOPK;

    hipMemsetAsync(accum, 0, 16, stream);
    hipMemsetAsync(best, 0xFF, (size_t)NB*MM*8, stream);

    k_valid<<<NB*MM/256, 256, 0, stream>>>(anchors, gt_boxes, valid);
    k_cost <<<NB*nchunk, 512, 0, stream>>>(pred_cls, pred_box, gt_boxes, gt_labels,
                                           valid, mask, cost_part, iou_part, accum, nchunk);
    k_merge<<<NB*NG/4,   256, 0, stream>>>(cost_part, iou_part, pred_cls, pred_box,
                                           gt_boxes, gt_labels, valid, best, nchunk);
    k_post <<<NB*MM/256, 256, 0, stream>>>(pred_cls, pred_box, gt_boxes, gt_labels,
                                           mask, best, accum);
    k_final<<<1, 64, 0, stream>>>(accum, out);
}